// Round 10
// baseline (352.837 us; speedup 1.0000x reference)
//
#include <hip/hip_runtime.h>
#include <cstdint>

typedef __attribute__((ext_vector_type(8))) __bf16 bf16x8;
typedef __attribute__((ext_vector_type(4))) __bf16 bf16x4;
typedef __attribute__((ext_vector_type(4))) float f32x4;

#define MFMA16(a, b, c) __builtin_amdgcn_mfma_f32_16x16x32_bf16((a), (b), (c), 0, 0, 0)
// counted waitcnt: NEVER drain vmcnt(0) in the main loop (T4).
#define WAITV(N) asm volatile("s_waitcnt vmcnt(" #N ")" ::: "memory")

static constexpr int SEQ = 2048;
static constexpr int DV = 256;
static constexpr float QK_SCALE = 4.5f;  // qk / INV_SCALE, INV_SCALE = 1/(0.5*9)

__device__ __forceinline__ bf16x4 cvt4(float4 v) {
    bf16x4 y;
    y[0] = (__bf16)v.x; y[1] = (__bf16)v.y; y[2] = (__bf16)v.z; y[3] = (__bf16)v.w;
    return y;
}

// async global->LDS DMA, 16B per lane; LDS dest wave-uniform base + lane*16.
__device__ __forceinline__ void gl_lds16(const void* g, void* l) {
    __builtin_amdgcn_global_load_lds((const __attribute__((address_space(1))) uint32_t*)g,
                                     (__attribute__((address_space(3))) uint32_t*)l, 16, 0, 0);
}

// ---------------------------------------------------------------------------
// Projection GEMM body. TRANS=1 writes r3 PACKED [b][kt=64][o=128][k=32] bf16,
// chunk-XOR baked (slot=(k>>3)^((o>>1)&3)).
// ---------------------------------------------------------------------------
template <int K, int TRANS>
__device__ __forceinline__ void proj_body(const float* __restrict__ X,
                                          const float* __restrict__ W,
                                          __bf16* __restrict__ out,
                                          float outScale, int m0, char* smem) {
    auto ldsX = (__bf16(*)[136])smem;                       // [64][136]
    auto ldsW = (__bf16(*)[136])(smem + 64 * 136 * 2);      // [128][136]

    const int t = threadIdx.x;
    const int w = t >> 6, l = t & 63, lrow = l & 15, lq = l >> 4;

    f32x4 acc[8];
#pragma unroll
    for (int i = 0; i < 8; ++i) acc[i] = f32x4{0.f, 0.f, 0.f, 0.f};

#pragma unroll
    for (int kh = 0; kh < K / 128; ++kh) {
        if (kh) __syncthreads();
#pragma unroll
        for (int i = 0; i < 8; ++i) {
            int idx = t + i * 256;
            int r = idx >> 5, c4 = idx & 31;
            float4 v = *(const float4*)(X + (size_t)(m0 + r) * K + kh * 128 + c4 * 4);
            *(bf16x4*)&ldsX[r][c4 * 4] = cvt4(v);
        }
#pragma unroll
        for (int i = 0; i < 16; ++i) {
            int idx = t + i * 256;
            int r = idx >> 5, c4 = idx & 31;
            float4 v = *(const float4*)(W + (size_t)r * K + kh * 128 + c4 * 4);
            *(bf16x4*)&ldsW[r][c4 * 4] = cvt4(v);
        }
        __syncthreads();

        bf16x8 aA[4];
#pragma unroll
        for (int kc = 0; kc < 4; ++kc)
            aA[kc] = *(const bf16x8*)((const char*)&ldsX[w * 16 + lrow][0] + kc * 64 + lq * 16);
#pragma unroll
        for (int nt = 0; nt < 8; ++nt) {
#pragma unroll
            for (int kc = 0; kc < 4; ++kc) {
                bf16x8 bB = *(const bf16x8*)((const char*)&ldsW[nt * 16 + lrow][0] + kc * 64 + lq * 16);
                acc[nt] = MFMA16(aA[kc], bB, acc[nt]);
            }
        }
    }

#pragma unroll
    for (int nt = 0; nt < 8; ++nt) {
        if (TRANS) {
            int gm = m0 + w * 16 + lq * 4;       // j = 0 global row
            int b = gm >> 11, s = gm & 2047;
            int col = nt * 16 + lrow;            // o
            int kt = s >> 5, s32 = s & 31;
            int slot = (s32 >> 3) ^ ((col >> 1) & 3);
            bf16x4 y;
#pragma unroll
            for (int j = 0; j < 4; ++j) y[j] = (__bf16)(acc[nt][j] * outScale);
            *(bf16x4*)(out + (((size_t)b * 64 + kt) * 128 + col) * 32 + slot * 8 + (s32 & 7)) = y;
        } else {
#pragma unroll
            for (int j = 0; j < 4; ++j) {
                int gm = m0 + w * 16 + lq * 4 + j;
                int col = nt * 16 + lrow;
                out[(size_t)gm * 128 + col] = (__bf16)(acc[nt][j] * outScale);
            }
        }
    }
}

// value [8][2048][256] fp32 -> vt PACKED [b][kt=64][v=256][k=32] bf16,
// chunk-XOR baked: slot = ((k>>3) ^ ((v>>1)&3)).
__device__ __forceinline__ void vt_body(const float* __restrict__ V,
                                        __bf16* __restrict__ vt, int wg, char* smem) {
    auto tile = (__bf16(*)[72])smem;   // [64][72]
    const int t = threadIdx.x;
    const int b = wg >> 7, by = (wg >> 5) & 3, bxx = wg & 31;
    const int s0 = bxx * 64, v0 = by * 64;
#pragma unroll
    for (int i = 0; i < 4; ++i) {
        int idx = t + i * 256;
        int r = idx >> 4, c4 = idx & 15;
        float4 x = *(const float4*)(V + ((size_t)b * SEQ + s0 + r) * DV + v0 + c4 * 4);
        *(bf16x4*)&tile[r][c4 * 4] = cvt4(x);
    }
    __syncthreads();
#pragma unroll
    for (int i = 0; i < 4; ++i) {
        int idx = t + i * 256;
        int vv = idx >> 4, c4 = idx & 15;
        bf16x4 y;
        y[0] = tile[c4 * 4 + 0][vv]; y[1] = tile[c4 * 4 + 1][vv];
        y[2] = tile[c4 * 4 + 2][vv]; y[3] = tile[c4 * 4 + 3][vv];
        int v = v0 + vv;
        int kt = (s0 >> 5) + (c4 >> 3);
        int slot = ((c4 >> 1) & 3) ^ ((v >> 1) & 3);
        *(bf16x4*)(vt + (((size_t)b * 64 + kt) * 256 + v) * 32 + slot * 8 + (c4 & 1) * 4) = y;
    }
}

// ---------------------------------------------------------------------------
// k_pre v2: producers in ONE launch, mask-cvt INTERLEAVED across the grid
// (odd bx of [0,2048) -> cvt wg) so its 201 MB HBM stream overlaps the
// compute-heavy projection/vt wgs in every dispatch round instead of running
// in the tail. Cvt unrolled 4x: 8 independent float4 loads in flight/thread.
// ---------------------------------------------------------------------------
__global__ __launch_bounds__(256) void k_pre(const float* __restrict__ q,
                                             const float* __restrict__ k,
                                             const float* __restrict__ v,
                                             const float* __restrict__ W0,
                                             const float* __restrict__ W1,
                                             const float* __restrict__ W2,
                                             const float* __restrict__ Wout,
                                             const float* __restrict__ mask,
                                             __bf16* __restrict__ r1s,
                                             __bf16* __restrict__ r2b,
                                             __bf16* __restrict__ r3t,
                                             __bf16* __restrict__ vtb,
                                             __bf16* __restrict__ wob,
                                             __bf16* __restrict__ maskb) {
    __shared__ __align__(16) char smem[52224];
    const int bx0 = blockIdx.x;
    int bx; bool is_cvt;
    if (bx0 < 2048) { is_cvt = (bx0 & 1); bx = bx0 >> 1; }   // cvt id / other id in [0,1024)
    else            { is_cvt = false; bx = 1024 + (bx0 - 2048); }  // other id [1024,1824)

    if (is_cvt) {
        // mask cvt: 33.55M elems; 1024 wgs x 256 thr x 8 elems = 2.097M/sweep,
        // 16 sweeps as 4 groups x 4-unrolled (8 loads in flight).
        const size_t stride = (size_t)1024 * 256 * 8;
        size_t base = ((size_t)bx * 256 + threadIdx.x) * 8;
#pragma unroll
        for (int g = 0; g < 4; ++g) {
            float4 a[4], b2[4];
            size_t i0 = base + (size_t)g * 4 * stride;
#pragma unroll
            for (int u = 0; u < 4; ++u) {
                a[u]  = *(const float4*)(mask + i0 + (size_t)u * stride);
                b2[u] = *(const float4*)(mask + i0 + (size_t)u * stride + 4);
            }
#pragma unroll
            for (int u = 0; u < 4; ++u) {
                bf16x8 o;
                o[0] = (__bf16)a[u].x; o[1] = (__bf16)a[u].y; o[2] = (__bf16)a[u].z; o[3] = (__bf16)a[u].w;
                o[4] = (__bf16)b2[u].x; o[5] = (__bf16)b2[u].y; o[6] = (__bf16)b2[u].z; o[7] = (__bf16)b2[u].w;
                *(bf16x8*)(maskb + i0 + (size_t)u * stride) = o;
            }
        }
        return;
    }

    if (bx < 256) {
        proj_body<128, 0>(q, W0, r1s, QK_SCALE, bx * 64, smem);
    } else if (bx < 512) {
        proj_body<128, 0>(k, W1, r2b, 1.0f, (bx - 256) * 64, smem);
    } else if (bx < 768) {
        proj_body<256, 1>(v, W2, r3t, 1.0f, (bx - 512) * 64, smem);
    } else if (bx < 1792) {
        vt_body(v, vtb, bx - 768, smem);
    } else {
        int i = (bx - 1792) * 256 + threadIdx.x;
        if (i < 8192) {
            float4 x = *(const float4*)(Wout + (size_t)i * 4);
            *(bf16x4*)(wob + (size_t)i * 4) = cvt4(x);
        }
    }
}

// ---------------------------------------------------------------------------
// Flash attention (byte-identical to round 9 — split-K x4, 2-buffer)
// ---------------------------------------------------------------------------
__global__ __launch_bounds__(256) void k_flash(const __bf16* __restrict__ r1s,
                                               const __bf16* __restrict__ r2,
                                               const __bf16* __restrict__ r3p,
                                               __bf16* __restrict__ v1p,
                                               float* __restrict__ ml) {
    __shared__ __align__(16) __bf16 r2s[2][32 * 128];   // 16 KB, s(r)=r&15
    __shared__ __align__(16) __bf16 r3s[2][128 * 32];   // 16 KB, s(r)=(r>>1)&3
    __shared__ __bf16 plds[4][16][48];                  // 6 KB, P C->A round-trip

    const int t = threadIdx.x;
    const int bx = (int)((blockIdx.x & 7) * 128 + (blockIdx.x >> 3));
    const int b = bx >> 7, rem = bx & 127, q0 = (rem >> 2) * 64, kh = rem & 3;
    const int w = t >> 6, l = t & 63, lrow = l & 15, lq = l >> 4;

    const __bf16* r1b = r1s + (size_t)b * SEQ * 128;
    const __bf16* r2b = r2 + (size_t)b * SEQ * 128 + (size_t)kh * 512 * 128;
    const __bf16* r3b = r3p + (size_t)b * 64 * 128 * 32 + (size_t)kh * 16 * 128 * 32;

    bf16x8 aQ[4];
    {
        const __bf16* p = r1b + (size_t)(q0 + w * 16 + lrow) * 128 + lq * 8;
#pragma unroll
        for (int kc = 0; kc < 4; ++kc) aQ[kc] = *(const bf16x8*)(p + kc * 32);
    }

    const __bf16* p_r2[2];
    const __bf16* p_r3[2];
#pragma unroll
    for (int q1 = 0; q1 < 2; ++q1) {
        int r = 8 * w + 4 * q1 + (l >> 4);
        int c = (l & 15) ^ (r & 15);
        p_r2[q1] = r2b + (size_t)r * 128 + c * 8;
        p_r3[q1] = r3b + (size_t)(2 * w + q1) * 512 + l * 8;
    }

    auto stage = [&](int bi) {
#pragma unroll
        for (int q1 = 0; q1 < 2; ++q1) {
            gl_lds16(p_r2[q1], &r2s[bi][(2 * w + q1) * 512]);
            gl_lds16(p_r3[q1], &r3s[bi][(2 * w + q1) * 512]);
            p_r2[q1] += 32 * 128;
            p_r3[q1] += 128 * 32;
        }
    };

    f32x4 acc[8];
#pragma unroll
    for (int i = 0; i < 8; ++i) acc[i] = f32x4{0.f, 0.f, 0.f, 0.f};
    float mrow[4] = {-INFINITY, -INFINITY, -INFINITY, -INFINITY};
    float lsum[4] = {0.f, 0.f, 0.f, 0.f};   // per-lane partial (deferred reduction)

    stage(0);
    for (int it = 0; it < 16; ++it) {
        if (it + 1 < 16) stage((it + 1) & 1);
        if (it < 15) { WAITV(4); } else { WAITV(0); }
        __builtin_amdgcn_s_barrier();
        __builtin_amdgcn_sched_barrier(0);
        const __bf16* R2 = &r2s[it & 1][0];
        const __bf16* R3 = &r3s[it & 1][0];

        f32x4 sc[2];
#pragma unroll
        for (int ct = 0; ct < 2; ++ct) {
            f32x4 s = f32x4{0.f, 0.f, 0.f, 0.f};
#pragma unroll
            for (int kc = 0; kc < 4; ++kc) {
                int p = (kc * 4 + lq) ^ lrow;
                bf16x8 bb = *(const bf16x8*)&R2[(ct * 16 + lrow) * 128 + p * 8];
                s = MFMA16(aQ[kc], bb, s);
            }
            sc[ct] = s;
        }

        float pm[4], al[4];
#pragma unroll
        for (int j = 0; j < 4; ++j) pm[j] = fmaxf(sc[0][j], sc[1][j]);
#pragma unroll
        for (int off = 1; off <= 8; off <<= 1)
#pragma unroll
            for (int j = 0; j < 4; ++j) pm[j] = fmaxf(pm[j], __shfl_xor(pm[j], off, 64));
#pragma unroll
        for (int j = 0; j < 4; ++j) {
            float mn = fmaxf(mrow[j], pm[j]);
            al[j] = __expf(mrow[j] - mn);
            mrow[j] = mn;
        }
        float pr[2][4];
#pragma unroll
        for (int ct = 0; ct < 2; ++ct)
#pragma unroll
            for (int j = 0; j < 4; ++j)
                pr[ct][j] = __expf(sc[ct][j] - mrow[j]);
#pragma unroll
        for (int j = 0; j < 4; ++j)
            lsum[j] = lsum[j] * al[j] + pr[0][j] + pr[1][j];
#pragma unroll
        for (int ot = 0; ot < 8; ++ot)
#pragma unroll
            for (int j = 0; j < 4; ++j) acc[ot][j] *= al[j];

#pragma unroll
        for (int ct = 0; ct < 2; ++ct)
#pragma unroll
            for (int j = 0; j < 4; ++j)
                plds[w][lq * 4 + j][ct * 16 + lrow] = (__bf16)pr[ct][j];
        __builtin_amdgcn_s_waitcnt(0xc07f);  // lgkmcnt(0) only — DMA stays in flight
        bf16x8 pA = *(const bf16x8*)&plds[w][lrow][lq * 8];

#pragma unroll
        for (int ot = 0; ot < 8; ++ot) {
            int p = lq ^ ((lrow >> 1) & 3);
            bf16x8 bb = *(const bf16x8*)&R3[(ot * 16 + lrow) * 32 + p * 8];
            acc[ot] = MFMA16(pA, bb, acc[ot]);
        }
        __builtin_amdgcn_s_barrier();   // trailing: protects buf reuse by stage
    }

#pragma unroll
    for (int off = 1; off <= 8; off <<= 1)
#pragma unroll
        for (int j = 0; j < 4; ++j) lsum[j] += __shfl_xor(lsum[j], off, 64);

    __bf16* vp = v1p + (size_t)kh * 8 * SEQ * 128;
#pragma unroll
    for (int ot = 0; ot < 8; ++ot)
#pragma unroll
        for (int j = 0; j < 4; ++j) {
            int q = q0 + w * 16 + lq * 4 + j;
            float v = acc[ot][j] / lsum[j];
            vp[((size_t)b * SEQ + q) * 128 + ot * 16 + lrow] = (__bf16)v;
        }
    if (lrow == 0) {
#pragma unroll
        for (int j = 0; j < 4; ++j) {
            size_t row = (size_t)b * SEQ + q0 + w * 16 + lq * 4 + j;
            ml[((size_t)kh * 8 * SEQ + row) * 2 + 0] = mrow[j];
            ml[((size_t)kh * 8 * SEQ + row) * 2 + 1] = lsum[j];
        }
    }
}

// ---------------------------------------------------------------------------
// out = mask@value + merge4(v1p)@Wout^T.  v10: 1024-THREAD WG (16 waves/CU,
// 2x r9) at IDENTICAL traffic/tile/LDS — the discriminating experiment for
// wave-FIFO vs per-CU-MSHR line-throughput models. grid 256 (1 wg/CU,
// XCD = batch), BM=64 x BN=256, BK=32. Waves 0-7: vt staging (2 instr/iter,
// 3-buf, WAITV(2)); waves 8-15: mask staging (1 instr/epoch=2 iters, 4-epoch
// buf, WAITV(2/1/0)). All 16 waves compute 16q x 64v (rg=w&3, cg=w>>2,
// acc=16 VGPR). LDS 80 KB.
// ---------------------------------------------------------------------------
__global__ __launch_bounds__(1024) void k_out(const __bf16* __restrict__ maskb,
                                              const __bf16* __restrict__ vtp,
                                              const __bf16* __restrict__ v1p,
                                              const float* __restrict__ ml,
                                              const __bf16* __restrict__ wob,
                                              float* __restrict__ out) {
    __shared__ __align__(16) __bf16 vbuf[3][256 * 32];  // 48 KB, slot-XOR baked
    __shared__ __align__(16) __bf16 mbuf[4][64 * 64];   // 32 KB, chunk-XOR baked

    const int t = threadIdx.x;
    const int bid = (int)((blockIdx.x & 7) * 32 + (blockIdx.x >> 3));  // XCD = batch
    const int m0 = bid * 64;
    const int b = m0 >> 11, q0 = m0 & 2047;
    const int w = t >> 6, l = t & 63, lrow = l & 15, lq = l >> 4;
    const int rg = w & 3, cg = w >> 2;   // 4 row-groups(16q) x 4 col-groups(64v)

    f32x4 acc[4];
#pragma unroll
    for (int i = 0; i < 4; ++i) acc[i] = f32x4{0.f, 0.f, 0.f, 0.f};

    // ---- staging pointers (role-split across 16 waves) ----
    const __bf16* vsrc[2];     // vt waves (w<8): 2 instrs/tile, 1 KB each
    const __bf16* msrc = nullptr;  // mask waves (w>=8): 1 instr/epoch (8 rows x 128 B)
    if (w < 8) {
#pragma unroll
        for (int i = 0; i < 2; ++i)
            vsrc[i] = vtp + (size_t)b * 64 * 8192 + (w * 2 + i) * 512 + l * 8;
    } else {
        const int m = w - 8;
        // lane l -> row 8m+(l>>3), stored slot l&7 holds chunk (l&7)^(l>>3)
        int c = (l & 7) ^ (l >> 3);
        msrc = maskb + ((size_t)(b * 2048 + q0 + 8 * m + (l >> 3))) * 2048 + c * 8;
    }

    // ---- prologue ----
    if (w < 8) {
#pragma unroll
        for (int kt = 0; kt < 2; ++kt)
#pragma unroll
            for (int i = 0; i < 2; ++i)
                gl_lds16(vsrc[i] + (size_t)kt * 8192, &vbuf[kt][(w * 2 + i) * 512]);
    } else {
        const int m = w - 8;
#pragma unroll
        for (int e = 0; e < 2; ++e)
            gl_lds16(msrc + (size_t)e * 64, &mbuf[e][m * 512]);
    }

    for (int it = 0; it < 64; ++it) {
        if (w >= 8) {
            const int m = w - 8;
            if ((it & 1) == 0) {
                int en = (it >> 1) + 2;
                if (en <= 31) gl_lds16(msrc + (size_t)en * 64, &mbuf[en & 3][m * 512]);
                if (it <= 58) { WAITV(2); } else if (it == 60) { WAITV(1); } else { WAITV(0); }
            }
        } else {
            if (it < 63) { WAITV(2); } else { WAITV(0); }
        }
        __builtin_amdgcn_s_barrier();
        __builtin_amdgcn_sched_barrier(0);
        if (w < 8 && it + 2 < 64) {
            int kt = it + 2;
#pragma unroll
            for (int i = 0; i < 2; ++i)
                gl_lds16(vsrc[i] + (size_t)kt * 8192, &vbuf[kt % 3][(w * 2 + i) * 512]);
        }
        __builtin_amdgcn_sched_barrier(0);

        // ---- compute (all 16 waves): 16q x 64v, BK=32 ----
        const __bf16* Mb = &mbuf[(it >> 1) & 3][0];
        const __bf16* V = &vbuf[it % 3][0];
        const int h = it & 1;
        bf16x8 aM = *(const bf16x8*)&Mb[(rg * 16 + lrow) * 64 + (((h * 4 + lq) ^ (lrow & 7)) * 8)];

        const int pv = lq ^ ((lrow >> 1) & 3);
#pragma unroll
        for (int vt8 = 0; vt8 < 4; ++vt8) {
            bf16x8 bb = *(const bf16x8*)&V[(cg * 64 + vt8 * 16 + lrow) * 32 + pv * 8];
            acc[vt8] = MFMA16(aM, bb, acc[vt8]);
        }
    }

    // ---- epilogue: 4-way split-K merge + v1@Wout^T ----
    const int NROW = 8 * SEQ;
    const int row = m0 + rg * 16 + lrow;
    float mp[4], lp[4];
    float mm = -INFINITY;
#pragma unroll
    for (int p = 0; p < 4; ++p) {
        mp[p] = ml[((size_t)p * NROW + row) * 2 + 0];
        lp[p] = ml[((size_t)p * NROW + row) * 2 + 1];
        mm = fmaxf(mm, mp[p]);
    }
    float wp[4], wsum = 0.f;
#pragma unroll
    for (int p = 0; p < 4; ++p) { wp[p] = lp[p] * __expf(mp[p] - mm); wsum += wp[p]; }
    float inv = 1.f / wsum;
#pragma unroll
    for (int p = 0; p < 4; ++p) wp[p] *= inv;

    bf16x8 aV[4];
#pragma unroll
    for (int oc = 0; oc < 4; ++oc) {
        float s[8];
#pragma unroll
        for (int j = 0; j < 8; ++j) s[j] = 0.f;
#pragma unroll
        for (int p = 0; p < 4; ++p) {
            bf16x8 x = *(const bf16x8*)(v1p + ((size_t)p * NROW + row) * 128 + oc * 32 + lq * 8);
#pragma unroll
            for (int j = 0; j < 8; ++j) s[j] += wp[p] * (float)x[j];
        }
#pragma unroll
        for (int j = 0; j < 8; ++j) aV[oc][j] = (__bf16)s[j];
    }
#pragma unroll
    for (int vt8 = 0; vt8 < 4; ++vt8) {
#pragma unroll
        for (int oc = 0; oc < 4; ++oc) {
            bf16x8 bb = *(const bf16x8*)(wob + (size_t)(cg * 64 + vt8 * 16 + lrow) * 128 + oc * 32 + lq * 8);
            acc[vt8] = MFMA16(aV[oc], bb, acc[vt8]);
        }
    }

#pragma unroll
    for (int vt8 = 0; vt8 < 4; ++vt8)
#pragma unroll
        for (int j = 0; j < 4; ++j) {
            int gq = m0 + rg * 16 + lq * 4 + j;
            out[(size_t)gq * 256 + cg * 64 + vt8 * 16 + lrow] = acc[vt8][j];
        }
}

// ---------------------------------------------------------------------------
extern "C" void kernel_launch(void* const* d_in, const int* in_sizes, int n_in,
                              void* d_out, int out_size, void* d_ws, size_t ws_size,
                              hipStream_t stream) {
    const float* q    = (const float*)d_in[0];
    const float* k    = (const float*)d_in[1];
    const float* v    = (const float*)d_in[2];
    const float* mask = (const float*)d_in[3];
    const float* W0   = (const float*)d_in[4];
    const float* W1   = (const float*)d_in[5];
    const float* W2   = (const float*)d_in[6];
    const float* Wout = (const float*)d_in[7];
    float* out = (float*)d_out;

    // tight workspace layout: 101 MB total
    char* ws = (char*)d_ws;
    __bf16* r1s = (__bf16*)(ws);                          // [0,4) MB
    __bf16* r2b = (__bf16*)(ws + (4ull << 20));           // [4,8) MB
    __bf16* r3t = (__bf16*)(ws + (8ull << 20));           // [8,12) MB PACKED
    __bf16* vtb = (__bf16*)(ws + (12ull << 20));          // [12,20) MB PACKED
    __bf16* wob = (__bf16*)(ws + (20ull << 20));          // [20, +64KB)
    float*  mlb = (float*)(ws + (20ull << 20) + (512ull << 10));  // [20.5, +512KB)
    __bf16* v1p = (__bf16*)(ws + (21ull << 20));          // [21,37) MB partials x4
    __bf16* mkb = (__bf16*)(ws + (37ull << 20));          // [37,101) MB bf16 mask

    k_pre<<<2848, 256, 0, stream>>>(q, k, v, W0, W1, W2, Wout, mask,
                                    r1s, r2b, r3t, vtb, wob, mkb);
    k_flash<<<1024, 256, 0, stream>>>(r1s, r2b, r3t, v1p, mlb);
    k_out<<<256, 1024, 0, stream>>>(mkb, vtb, v1p, mlb, wob, out);
}

// Round 11
// 324.131 us; speedup vs baseline: 1.0886x; 1.0886x over previous
//
#include <hip/hip_runtime.h>
#include <cstdint>

typedef __attribute__((ext_vector_type(8))) __bf16 bf16x8;
typedef __attribute__((ext_vector_type(4))) __bf16 bf16x4;
typedef __attribute__((ext_vector_type(4))) float f32x4;

#define MFMA16(a, b, c) __builtin_amdgcn_mfma_f32_16x16x32_bf16((a), (b), (c), 0, 0, 0)
// counted waitcnt: NEVER drain vmcnt(0) in the main loop (T4).
#define WAITV(N) asm volatile("s_waitcnt vmcnt(" #N ")" ::: "memory")

static constexpr int SEQ = 2048;
static constexpr int DV = 256;
static constexpr float QK_SCALE = 4.5f;  // qk / INV_SCALE, INV_SCALE = 1/(0.5*9)

__device__ __forceinline__ bf16x4 cvt4(float4 v) {
    bf16x4 y;
    y[0] = (__bf16)v.x; y[1] = (__bf16)v.y; y[2] = (__bf16)v.z; y[3] = (__bf16)v.w;
    return y;
}

// async global->LDS DMA, 16B per lane; LDS dest wave-uniform base + lane*16.
__device__ __forceinline__ void gl_lds16(const void* g, void* l) {
    __builtin_amdgcn_global_load_lds((const __attribute__((address_space(1))) uint32_t*)g,
                                     (__attribute__((address_space(3))) uint32_t*)l, 16, 0, 0);
}

// ---------------------------------------------------------------------------
// Projection GEMM body. TRANS=1 writes r3 PACKED [b][kt=64][o=128][k=32] bf16,
// chunk-XOR baked (slot=(k>>3)^((o>>1)&3)).
// ---------------------------------------------------------------------------
template <int K, int TRANS>
__device__ __forceinline__ void proj_body(const float* __restrict__ X,
                                          const float* __restrict__ W,
                                          __bf16* __restrict__ out,
                                          float outScale, int m0, char* smem) {
    auto ldsX = (__bf16(*)[136])smem;                       // [64][136]
    auto ldsW = (__bf16(*)[136])(smem + 64 * 136 * 2);      // [128][136]

    const int t = threadIdx.x;
    const int w = t >> 6, l = t & 63, lrow = l & 15, lq = l >> 4;

    f32x4 acc[8];
#pragma unroll
    for (int i = 0; i < 8; ++i) acc[i] = f32x4{0.f, 0.f, 0.f, 0.f};

#pragma unroll
    for (int kh = 0; kh < K / 128; ++kh) {
        if (kh) __syncthreads();
#pragma unroll
        for (int i = 0; i < 8; ++i) {
            int idx = t + i * 256;
            int r = idx >> 5, c4 = idx & 31;
            float4 v = *(const float4*)(X + (size_t)(m0 + r) * K + kh * 128 + c4 * 4);
            *(bf16x4*)&ldsX[r][c4 * 4] = cvt4(v);
        }
#pragma unroll
        for (int i = 0; i < 16; ++i) {
            int idx = t + i * 256;
            int r = idx >> 5, c4 = idx & 31;
            float4 v = *(const float4*)(W + (size_t)r * K + kh * 128 + c4 * 4);
            *(bf16x4*)&ldsW[r][c4 * 4] = cvt4(v);
        }
        __syncthreads();

        bf16x8 aA[4];
#pragma unroll
        for (int kc = 0; kc < 4; ++kc)
            aA[kc] = *(const bf16x8*)((const char*)&ldsX[w * 16 + lrow][0] + kc * 64 + lq * 16);
#pragma unroll
        for (int nt = 0; nt < 8; ++nt) {
#pragma unroll
            for (int kc = 0; kc < 4; ++kc) {
                bf16x8 bB = *(const bf16x8*)((const char*)&ldsW[nt * 16 + lrow][0] + kc * 64 + lq * 16);
                acc[nt] = MFMA16(aA[kc], bB, acc[nt]);
            }
        }
    }

#pragma unroll
    for (int nt = 0; nt < 8; ++nt) {
        if (TRANS) {
            int gm = m0 + w * 16 + lq * 4;       // j = 0 global row
            int b = gm >> 11, s = gm & 2047;
            int col = nt * 16 + lrow;            // o
            int kt = s >> 5, s32 = s & 31;
            int slot = (s32 >> 3) ^ ((col >> 1) & 3);
            bf16x4 y;
#pragma unroll
            for (int j = 0; j < 4; ++j) y[j] = (__bf16)(acc[nt][j] * outScale);
            *(bf16x4*)(out + (((size_t)b * 64 + kt) * 128 + col) * 32 + slot * 8 + (s32 & 7)) = y;
        } else {
#pragma unroll
            for (int j = 0; j < 4; ++j) {
                int gm = m0 + w * 16 + lq * 4 + j;
                int col = nt * 16 + lrow;
                out[(size_t)gm * 128 + col] = (__bf16)(acc[nt][j] * outScale);
            }
        }
    }
}

// value [8][2048][256] fp32 -> vt PACKED [b][kt=64][v=256][k=32] bf16,
// chunk-XOR baked: slot = ((k>>3) ^ ((v>>1)&3)).
__device__ __forceinline__ void vt_body(const float* __restrict__ V,
                                        __bf16* __restrict__ vt, int wg, char* smem) {
    auto tile = (__bf16(*)[72])smem;   // [64][72]
    const int t = threadIdx.x;
    const int b = wg >> 7, by = (wg >> 5) & 3, bxx = wg & 31;
    const int s0 = bxx * 64, v0 = by * 64;
#pragma unroll
    for (int i = 0; i < 4; ++i) {
        int idx = t + i * 256;
        int r = idx >> 4, c4 = idx & 15;
        float4 x = *(const float4*)(V + ((size_t)b * SEQ + s0 + r) * DV + v0 + c4 * 4);
        *(bf16x4*)&tile[r][c4 * 4] = cvt4(x);
    }
    __syncthreads();
#pragma unroll
    for (int i = 0; i < 4; ++i) {
        int idx = t + i * 256;
        int vv = idx >> 4, c4 = idx & 15;
        bf16x4 y;
        y[0] = tile[c4 * 4 + 0][vv]; y[1] = tile[c4 * 4 + 1][vv];
        y[2] = tile[c4 * 4 + 2][vv]; y[3] = tile[c4 * 4 + 3][vv];
        int v = v0 + vv;
        int kt = (s0 >> 5) + (c4 >> 3);
        int slot = ((c4 >> 1) & 3) ^ ((v >> 1) & 3);
        *(bf16x4*)(vt + (((size_t)b * 64 + kt) * 256 + v) * 32 + slot * 8 + (c4 & 1) * 4) = y;
    }
}

// ---------------------------------------------------------------------------
// k_pre (r6 form — NO mask prepass; that was a net loss: +25 us here to save
// -14 us downstream). Projections + vt + Wout cvt. grid 1824, 3 wg/CU.
// ---------------------------------------------------------------------------
__global__ __launch_bounds__(256) void k_pre(const float* __restrict__ q,
                                             const float* __restrict__ k,
                                             const float* __restrict__ v,
                                             const float* __restrict__ W0,
                                             const float* __restrict__ W1,
                                             const float* __restrict__ W2,
                                             const float* __restrict__ Wout,
                                             __bf16* __restrict__ r1s,
                                             __bf16* __restrict__ r2b,
                                             __bf16* __restrict__ r3t,
                                             __bf16* __restrict__ vtb,
                                             __bf16* __restrict__ wob) {
    __shared__ __align__(16) char smem[52224];
    const int bx = blockIdx.x;
    if (bx < 256) {
        proj_body<128, 0>(q, W0, r1s, QK_SCALE, bx * 64, smem);
    } else if (bx < 512) {
        proj_body<128, 0>(k, W1, r2b, 1.0f, (bx - 256) * 64, smem);
    } else if (bx < 768) {
        proj_body<256, 1>(v, W2, r3t, 1.0f, (bx - 512) * 64, smem);
    } else if (bx < 1792) {
        vt_body(v, vtb, bx - 768, smem);
    } else {
        int i = (bx - 1792) * 256 + threadIdx.x;
        if (i < 8192) {
            float4 x = *(const float4*)(Wout + (size_t)i * 4);
            *(bf16x4*)(wob + (size_t)i * 4) = cvt4(x);
        }
    }
}

// ---------------------------------------------------------------------------
// FLASH role body (two independent 4-wave units per 512-thr wg; identical
// loop structure -> shared wg barrier is safe; vmcnt ledger is per-wave).
// Split-K x4, 2-buffer, counted vmcnt — byte-identical logic to round 9.
// Per-unit LDS: 38 KB slice of smem.
// ---------------------------------------------------------------------------
__device__ __forceinline__ void flash_body(const __bf16* __restrict__ r1s,
                                           const __bf16* __restrict__ r2,
                                           const __bf16* __restrict__ r3p,
                                           __bf16* __restrict__ v1p,
                                           float* __restrict__ ml,
                                           int jf, char* smem) {
    const int t = threadIdx.x;
    const int unit = t >> 8, t8 = t & 255;
    const int f = jf * 2 + unit;                 // flash unit id in [0,1024)
    const int b = f >> 7, rem = f & 127, q0 = (rem >> 2) * 64, kh = rem & 3;
    const int w = t8 >> 6, l = t8 & 63, lrow = l & 15, lq = l >> 4;

    __bf16* r2s = (__bf16*)(smem + unit * 38912);            // [2][4096]
    __bf16* r3s = (__bf16*)(smem + unit * 38912 + 16384);    // [2][4096]
    __bf16* plds = (__bf16*)(smem + unit * 38912 + 32768);   // [4][16*48]

    const __bf16* r1b = r1s + (size_t)b * SEQ * 128;
    const __bf16* r2b = r2 + (size_t)b * SEQ * 128 + (size_t)kh * 512 * 128;
    const __bf16* r3b = r3p + (size_t)b * 64 * 128 * 32 + (size_t)kh * 16 * 128 * 32;

    bf16x8 aQ[4];
    {
        const __bf16* p = r1b + (size_t)(q0 + w * 16 + lrow) * 128 + lq * 8;
#pragma unroll
        for (int kc = 0; kc < 4; ++kc) aQ[kc] = *(const bf16x8*)(p + kc * 32);
    }

    const __bf16* p_r2[2];
    const __bf16* p_r3[2];
#pragma unroll
    for (int q1 = 0; q1 < 2; ++q1) {
        int r = 8 * w + 4 * q1 + (l >> 4);
        int c = (l & 15) ^ (r & 15);
        p_r2[q1] = r2b + (size_t)r * 128 + c * 8;
        p_r3[q1] = r3b + (size_t)(2 * w + q1) * 512 + l * 8;
    }

    auto stage = [&](int bi) {
#pragma unroll
        for (int q1 = 0; q1 < 2; ++q1) {
            gl_lds16(p_r2[q1], r2s + bi * 4096 + (2 * w + q1) * 512);
            gl_lds16(p_r3[q1], r3s + bi * 4096 + (2 * w + q1) * 512);
            p_r2[q1] += 32 * 128;
            p_r3[q1] += 128 * 32;
        }
    };

    f32x4 acc[8];
#pragma unroll
    for (int i = 0; i < 8; ++i) acc[i] = f32x4{0.f, 0.f, 0.f, 0.f};
    float mrow[4] = {-INFINITY, -INFINITY, -INFINITY, -INFINITY};
    float lsum[4] = {0.f, 0.f, 0.f, 0.f};   // per-lane partial (deferred reduction)

    stage(0);
    for (int it = 0; it < 16; ++it) {
        if (it + 1 < 16) stage((it + 1) & 1);
        if (it < 15) { WAITV(4); } else { WAITV(0); }
        __builtin_amdgcn_s_barrier();
        __builtin_amdgcn_sched_barrier(0);
        const __bf16* R2 = r2s + (it & 1) * 4096;
        const __bf16* R3 = r3s + (it & 1) * 4096;

        f32x4 sc[2];
#pragma unroll
        for (int ct = 0; ct < 2; ++ct) {
            f32x4 s = f32x4{0.f, 0.f, 0.f, 0.f};
#pragma unroll
            for (int kc = 0; kc < 4; ++kc) {
                int p = (kc * 4 + lq) ^ lrow;
                bf16x8 bb = *(const bf16x8*)&R2[(ct * 16 + lrow) * 128 + p * 8];
                s = MFMA16(aQ[kc], bb, s);
            }
            sc[ct] = s;
        }

        float pm[4], al[4];
#pragma unroll
        for (int j = 0; j < 4; ++j) pm[j] = fmaxf(sc[0][j], sc[1][j]);
#pragma unroll
        for (int off = 1; off <= 8; off <<= 1)
#pragma unroll
            for (int j = 0; j < 4; ++j) pm[j] = fmaxf(pm[j], __shfl_xor(pm[j], off, 64));
#pragma unroll
        for (int j = 0; j < 4; ++j) {
            float mn = fmaxf(mrow[j], pm[j]);
            al[j] = __expf(mrow[j] - mn);
            mrow[j] = mn;
        }
        float pr[2][4];
#pragma unroll
        for (int ct = 0; ct < 2; ++ct)
#pragma unroll
            for (int j = 0; j < 4; ++j)
                pr[ct][j] = __expf(sc[ct][j] - mrow[j]);
#pragma unroll
        for (int j = 0; j < 4; ++j)
            lsum[j] = lsum[j] * al[j] + pr[0][j] + pr[1][j];
#pragma unroll
        for (int ot = 0; ot < 8; ++ot)
#pragma unroll
            for (int j = 0; j < 4; ++j) acc[ot][j] *= al[j];

#pragma unroll
        for (int ct = 0; ct < 2; ++ct)
#pragma unroll
            for (int j = 0; j < 4; ++j)
                plds[w * 768 + (lq * 4 + j) * 48 + ct * 16 + lrow] = (__bf16)pr[ct][j];
        __builtin_amdgcn_s_waitcnt(0xc07f);  // lgkmcnt(0) only — DMA stays in flight
        bf16x8 pA = *(const bf16x8*)&plds[w * 768 + lrow * 48 + lq * 8];

#pragma unroll
        for (int ot = 0; ot < 8; ++ot) {
            int p = lq ^ ((lrow >> 1) & 3);
            bf16x8 bb = *(const bf16x8*)&R3[(ot * 16 + lrow) * 32 + p * 8];
            acc[ot] = MFMA16(pA, bb, acc[ot]);
        }
        __builtin_amdgcn_s_barrier();   // trailing: protects buf reuse by stage
    }

#pragma unroll
    for (int off = 1; off <= 8; off <<= 1)
#pragma unroll
        for (int j = 0; j < 4; ++j) lsum[j] += __shfl_xor(lsum[j], off, 64);

    __bf16* vp = v1p + (size_t)kh * 8 * SEQ * 128;
#pragma unroll
    for (int ot = 0; ot < 8; ++ot)
#pragma unroll
        for (int j = 0; j < 4; ++j) {
            int q = q0 + w * 16 + lq * 4 + j;
            float v = acc[ot][j] / lsum[j];
            vp[((size_t)b * SEQ + q) * 128 + ot * 16 + lrow] = (__bf16)v;
        }
    if (lrow == 0) {
#pragma unroll
        for (int j = 0; j < 4; ++j) {
            size_t row = (size_t)b * SEQ + q0 + w * 16 + lq * 4 + j;
            ml[((size_t)kh * 8 * SEQ + row) * 2 + 0] = mrow[j];
            ml[((size_t)kh * 8 * SEQ + row) * 2 + 1] = lsum[j];
        }
    }
}

// ---------------------------------------------------------------------------
// MV role body: out = mask@value (fp32 mask read directly — r6's proven
// structure). BM=32, 8 waves: w<4 vt staging (vbuf[3], WAITV(4)), w>=4 mask
// staging (mbuf[4] fp32, WAITV(3/2/0) even iters). Writes f32 `out` (the
// Wout term is added by k_epi).
// ---------------------------------------------------------------------------
__device__ __forceinline__ void mv_body(const float* __restrict__ mask,
                                        const __bf16* __restrict__ vtp,
                                        float* __restrict__ out,
                                        int jm, char* smem) {
    float* mbuf = (float*)smem;                       // [4][32*64] f32 = 32 KB
    __bf16* vbuf = (__bf16*)(smem + 32768);           // [3][256*32] = 48 KB

    const int t = threadIdx.x;
    const int b = jm & 7, qblk = jm >> 3;   // XCD(bx)=bx%8 == jm%8 -> batch/XCD affinity
    const int m0 = b * 2048 + qblk * 32, q0 = qblk * 32;
    const int w = t >> 6, l = t & 63, lrow = l & 15, lq = l >> 4;
    const int rg = w & 1, ch = w >> 1;   // 2 row-groups(16q) x 4... ch in [0,4): col-128-half via w>>1? 

    // NOTE: 8 waves -> rg = w&1 (16 rows), ch = w>>1 in [0,4) would over-cover;
    // use r6 mapping: waves 0..7 compute, rg=w&1, col-half ch2=(w>>1)&1? r6 had
    // 8 waves = 2 rg x 4 cg(64v). Keep r6 exactly: cg = w>>1 in [0,4), 64v each.
    const int cg = w >> 1;               // 4 col-groups x 64 v

    f32x4 acc[4];
#pragma unroll
    for (int i = 0; i < 4; ++i) acc[i] = f32x4{0.f, 0.f, 0.f, 0.f};

    const __bf16* vsrc[4];
    const float* msrc[2];
    if (w < 4) {
#pragma unroll
        for (int i = 0; i < 4; ++i)
            vsrc[i] = vtp + (size_t)b * 64 * 8192 + (w * 4 + i) * 512 + l * 8;
    } else {
        const int m = w - 4;
#pragma unroll
        for (int s = 0; s < 2; ++s) {
            int r = 4 * (m * 2 + s) + (l >> 4);
            int c = (l & 15) ^ (r & 7);
            msrc[s] = mask + ((size_t)(b * 2048 + q0 + r)) * 2048 + c * 4;
        }
    }

    if (w < 4) {
#pragma unroll
        for (int kt = 0; kt < 2; ++kt)
#pragma unroll
            for (int i = 0; i < 4; ++i)
                gl_lds16(vsrc[i] + (size_t)kt * 8192, vbuf + kt * 8192 + (w * 4 + i) * 512);
    } else {
        const int m = w - 4;
#pragma unroll
        for (int e = 0; e < 2; ++e)
#pragma unroll
            for (int s = 0; s < 2; ++s)
                gl_lds16(msrc[s] + (size_t)e * 64, mbuf + e * 2048 + (m * 2 + s) * 256);
    }

    for (int it = 0; it < 64; ++it) {
        if (w >= 4) {
            const int m = w - 4;
            if (it <= 59) {
                int en = (it >> 1) + 2, s = it & 1;
                gl_lds16(msrc[s] + (size_t)en * 64, mbuf + (en & 3) * 2048 + (m * 2 + s) * 256);
            }
            if ((it & 1) == 0) {
                if (it <= 58) { WAITV(3); } else if (it == 60) { WAITV(2); } else { WAITV(0); }
            }
        } else {
            if (it < 63) { WAITV(4); } else { WAITV(0); }
        }
        __builtin_amdgcn_s_barrier();
        __builtin_amdgcn_sched_barrier(0);
        if (w < 4 && it + 2 < 64) {
            int kt = it + 2;
#pragma unroll
            for (int i = 0; i < 4; ++i)
                gl_lds16(vsrc[i] + (size_t)kt * 8192, vbuf + (kt % 3) * 8192 + (w * 4 + i) * 512);
        }
        __builtin_amdgcn_sched_barrier(0);

        // compute: 16q x 64v, BK=32
        const float* Mb = mbuf + ((it >> 1) & 3) * 2048;
        const __bf16* V = vbuf + (it % 3) * 8192;
        const int h = it & 1;
        int c0 = (h * 8 + lq * 2) ^ (lrow & 7);
        int c1 = (h * 8 + lq * 2 + 1) ^ (lrow & 7);
        float4 f0 = *(const float4*)&Mb[(rg * 16 + lrow) * 64 + c0 * 4];
        float4 f1 = *(const float4*)&Mb[(rg * 16 + lrow) * 64 + c1 * 4];
        bf16x8 aM;
        aM[0] = (__bf16)f0.x; aM[1] = (__bf16)f0.y; aM[2] = (__bf16)f0.z; aM[3] = (__bf16)f0.w;
        aM[4] = (__bf16)f1.x; aM[5] = (__bf16)f1.y; aM[6] = (__bf16)f1.z; aM[7] = (__bf16)f1.w;

        const int pv = lq ^ ((lrow >> 1) & 3);
#pragma unroll
        for (int vt8 = 0; vt8 < 4; ++vt8) {
            bf16x8 bb = *(const bf16x8*)&V[(cg * 64 + vt8 * 16 + lrow) * 32 + pv * 8];
            acc[vt8] = MFMA16(aM, bb, acc[vt8]);
        }
    }

    // write mask@value partial (f32); Wout term added by k_epi
#pragma unroll
    for (int vt8 = 0; vt8 < 4; ++vt8)
#pragma unroll
        for (int j = 0; j < 4; ++j) {
            int gq = m0 + rg * 16 + lq * 4 + j;
            out[(size_t)gq * 256 + cg * 64 + vt8 * 16 + lrow] = acc[vt8][j];
        }
}

// ---------------------------------------------------------------------------
// k_fused: flash (512 wgs x 2 units) + mv (512 wgs) in ONE launch.
// role = (bx>>8)&1 so first-fill co-resident pairs (i, i+256) are F+M —
// complementary bottlenecks (flash: latency/VALU, HBM idle; mv: HBM stream,
// SIMD idle) overlap on each CU. LDS 80 KB -> 2 wg/CU.
// ---------------------------------------------------------------------------
__global__ __launch_bounds__(512, 4) void k_fused(const __bf16* __restrict__ r1s,
                                                  const __bf16* __restrict__ r2b,
                                                  const __bf16* __restrict__ r3t,
                                                  __bf16* __restrict__ v1p,
                                                  float* __restrict__ mlb,
                                                  const float* __restrict__ mask,
                                                  const __bf16* __restrict__ vtp,
                                                  float* __restrict__ out) {
    __shared__ __align__(16) char smem[81920];
    const int bx = blockIdx.x;
    if (((bx >> 8) & 1) == 0) {
        int jf = (bx < 256) ? bx : bx - 256;          // [0,512)
        flash_body(r1s, r2b, r3t, v1p, mlb, jf, smem);
    } else {
        int jm = (bx < 512) ? bx - 256 : bx - 512;    // [0,256) ∪ [256,512)
        if (bx >= 768) jm = bx - 512;                 // [256,512)
        else jm = bx - 256;                           // [0,256)
        mv_body(mask, vtp, out, jm, smem);
    }
}

// ---------------------------------------------------------------------------
// k_epi: out += merge4(v1p) @ Wout^T. grid 512 x 256 thr, 32 rows/wg.
// ---------------------------------------------------------------------------
__global__ __launch_bounds__(256) void k_epi(const __bf16* __restrict__ v1p,
                                             const float* __restrict__ ml,
                                             const __bf16* __restrict__ wob,
                                             float* __restrict__ out) {
    const int t = threadIdx.x;
    const int m0 = blockIdx.x * 32;
    const int w = t >> 6, l = t & 63, lrow = l & 15, lq = l >> 4;
    const int rg = w & 1, ch = w >> 1;   // 2 row-groups(16) x 2 col-halves(128)

    const int NROW = 8 * SEQ;
    const int row = m0 + rg * 16 + lrow;
    float mp[4], lp[4];
    float mm = -INFINITY;
#pragma unroll
    for (int p = 0; p < 4; ++p) {
        mp[p] = ml[((size_t)p * NROW + row) * 2 + 0];
        lp[p] = ml[((size_t)p * NROW + row) * 2 + 1];
        mm = fmaxf(mm, mp[p]);
    }
    float wp[4], wsum = 0.f;
#pragma unroll
    for (int p = 0; p < 4; ++p) { wp[p] = lp[p] * __expf(mp[p] - mm); wsum += wp[p]; }
    float inv = 1.f / wsum;
#pragma unroll
    for (int p = 0; p < 4; ++p) wp[p] *= inv;

    bf16x8 aV[4];
#pragma unroll
    for (int oc = 0; oc < 4; ++oc) {
        float s[8];
#pragma unroll
        for (int j = 0; j < 8; ++j) s[j] = 0.f;
#pragma unroll
        for (int p = 0; p < 4; ++p) {
            bf16x8 x = *(const bf16x8*)(v1p + ((size_t)p * NROW + row) * 128 + oc * 32 + lq * 8);
#pragma unroll
            for (int j = 0; j < 8; ++j) s[j] += wp[p] * (float)x[j];
        }
#pragma unroll
        for (int j = 0; j < 8; ++j) aV[oc][j] = (__bf16)s[j];
    }

    f32x4 acc[8];
#pragma unroll
    for (int i = 0; i < 8; ++i) acc[i] = f32x4{0.f, 0.f, 0.f, 0.f};
#pragma unroll
    for (int vt8 = 0; vt8 < 8; ++vt8) {
#pragma unroll
        for (int oc = 0; oc < 4; ++oc) {
            bf16x8 bb = *(const bf16x8*)(wob + (size_t)(ch * 128 + vt8 * 16 + lrow) * 128 + oc * 32 + lq * 8);
            acc[vt8] = MFMA16(aV[oc], bb, acc[vt8]);
        }
    }

#pragma unroll
    for (int vt8 = 0; vt8 < 8; ++vt8)
#pragma unroll
        for (int j = 0; j < 4; ++j) {
            int gq = m0 + rg * 16 + lq * 4 + j;
            size_t o = (size_t)gq * 256 + ch * 128 + vt8 * 16 + lrow;
            out[o] += acc[vt8][j];
        }
}

// ---------------------------------------------------------------------------
extern "C" void kernel_launch(void* const* d_in, const int* in_sizes, int n_in,
                              void* d_out, int out_size, void* d_ws, size_t ws_size,
                              hipStream_t stream) {
    const float* q    = (const float*)d_in[0];
    const float* k    = (const float*)d_in[1];
    const float* v    = (const float*)d_in[2];
    const float* mask = (const float*)d_in[3];
    const float* W0   = (const float*)d_in[4];
    const float* W1   = (const float*)d_in[5];
    const float* W2   = (const float*)d_in[6];
    const float* Wout = (const float*)d_in[7];
    float* out = (float*)d_out;

    char* ws = (char*)d_ws;
    __bf16* r1s = (__bf16*)(ws);                          // [0,4) MB
    __bf16* r2b = (__bf16*)(ws + (4ull << 20));           // [4,8) MB
    __bf16* r3t = (__bf16*)(ws + (8ull << 20));           // [8,12) MB PACKED
    __bf16* vtb = (__bf16*)(ws + (12ull << 20));          // [12,20) MB PACKED
    __bf16* wob = (__bf16*)(ws + (20ull << 20));          // [20, +64KB)
    float*  mlb = (float*)(ws + (20ull << 20) + (512ull << 10));  // [20.5, +512KB)
    __bf16* v1p = (__bf16*)(ws + (21ull << 20));          // [21,37) MB partials x4

    k_pre<<<1824, 256, 0, stream>>>(q, k, v, W0, W1, W2, Wout,
                                    r1s, r2b, r3t, vtb, wob);
    k_fused<<<1024, 512, 0, stream>>>(r1s, r2b, r3t, v1p, mlb, mask, vtb, out);
    k_epi<<<512, 256, 0, stream>>>(v1p, mlb, wob, out);
}